// Round 17
// baseline (430.782 us; speedup 1.0000x reference)
//
#include <hip/hip_runtime.h>
#include <hip/hip_bf16.h>

#define NB   4
#define CCH  256
#define CQK  32
#define NTOK 4096
#define LOG2E 1.4426950408889634f

typedef unsigned short u16;
typedef unsigned int   u32;
typedef __attribute__((ext_vector_type(8))) __bf16 bf16x8;
typedef __attribute__((ext_vector_type(4))) float  f32x4;
typedef __attribute__((ext_vector_type(4))) u32    u32x4;

union bfu { bf16x8 v; u16 s[8]; u32 w[4]; };

static __device__ __forceinline__ u16 f2bf(float f) {
  union { __hip_bfloat16 h; u16 u; } c; c.h = __float2bfloat16(f); return c.u;
}
static __device__ __forceinline__ float bf2f(u16 u) {
  union { __hip_bfloat16 h; u16 u; } c; c.u = u; return __bfloat162float(c.h);
}
// Safe packed f32->bf16 pair (round-half-up, ~ulp of RNE). Plain integer ops
// (R11's v_cvt_pk_bf16_f32 asm was the correctness poison — do not reuse).
static __device__ __forceinline__ u32 pkbf(float a, float b) {
  u32 ua = __builtin_bit_cast(u32, a) + 0x8000u;
  u32 ub = __builtin_bit_cast(u32, b) + 0x8000u;
  return (ua >> 16) | (ub & 0xFFFF0000u);
}
static __device__ __forceinline__ f32x4 mfma16(bf16x8 a, bf16x8 b, f32x4 c) {
  return __builtin_amdgcn_mfma_f32_16x16x32_bf16(a, b, c, 0, 0, 0);
}

// V tiled layout (since R9): per (b, ch=m/64) a contiguous 32KB slab
// [ct 16][mh 2][512 u16]; u16 slot (hi*16+lo)*8+j =
// V[m=ch*64+mh*32+16*(j>>2)+4hi+(j&3)][c=ct*16+lo].

// ---------------- Kernel 0: split W to bf16 hi/lo (once, tiny) ----------------
__global__ __launch_bounds__(256) void convert_w(
    const float* __restrict__ wq, const float* __restrict__ wk,
    const float* __restrict__ wv, u16* __restrict__ whi, u16* __restrict__ wlo)
{
  int i   = blockIdx.x * 256 + threadIdx.x;  // float4 index, 320*64 total
  int row = i >> 6;
  int col = (i & 63) * 4;
  const float* src = (row < 32) ? wq + row * CCH
                   : (row < 64) ? wk + (row - 32) * CCH
                                : wv + (row - 64) * CCH;
  float sc = (row < 32) ? LOG2E : 1.0f;
  float4 v = *(const float4*)(src + col);
  float f[4] = { v.x * sc, v.y * sc, v.z * sc, v.w * sc };
  u16 h[4], l[4];
#pragma unroll
  for (int j = 0; j < 4; j++) {
    h[j] = f2bf(f[j]);
    l[j] = f2bf(f[j] - bf2f(h[j]));
  }
  uint2 ph = { (u32)h[0] | ((u32)h[1] << 16), (u32)h[2] | ((u32)h[3] << 16) };
  uint2 pl = { (u32)l[0] | ((u32)l[1] << 16), (u32)l[2] | ((u32)l[3] << 16) };
  *(uint2*)(whi + (size_t)i * 4) = ph;
  *(uint2*)(wlo + (size_t)i * 4) = pl;
}

// ---------------- Kernel 1: MFMA QKV projection (R13 version: n-tile 32) -----
__attribute__((amdgpu_waves_per_eu(2, 4)))
__global__ __launch_bounds__(256) void qkv_proj(
    const float* __restrict__ x,
    const float* __restrict__ bq, const float* __restrict__ bk,
    const float* __restrict__ bv,
    const u16* __restrict__ whi, const u16* __restrict__ wlo,
    u16* __restrict__ Qo, u16* __restrict__ Ko, u16* __restrict__ Vo)
{
  const int nt = blockIdx.x;
  const int b  = blockIdx.y;
  const int n0 = nt * 32;
  const int tid = threadIdx.x;
  const int w = tid >> 6, lane = tid & 63, lo = lane & 15, hi = lane >> 4;

  const f32x4 fz = { 0.f, 0.f, 0.f, 0.f };
  f32x4 acc[5][2];
#pragma unroll
  for (int t = 0; t < 5; t++) { acc[t][0] = fz; acc[t][1] = fz; }

  const float* xb = x + (size_t)b * CCH * NTOK;

  for (int k = 0; k < 8; k++) {
    const int ck = k * 32;
    bf16x8 xh[2], xl[2];
#pragma unroll
    for (int nt2 = 0; nt2 < 2; nt2++) {
      const float* xc = xb + (size_t)(ck + hi * 8) * NTOK + n0 + nt2 * 16 + lo;
      u32  bw[8];
      float rl[8];
#pragma unroll
      for (int j = 0; j < 8; j++) {
        float f  = xc[(size_t)j * NTOK];
        u32 bits = __builtin_bit_cast(u32, f);
        float fh = __builtin_bit_cast(float, bits & 0xFFFF0000u);
        bw[j] = bits;
        rl[j] = f - fh;
      }
      bfu H, L;
#pragma unroll
      for (int j = 0; j < 4; j++) {
        H.w[j] = (bw[2 * j] >> 16) | (bw[2 * j + 1] & 0xFFFF0000u);
        L.w[j] = pkbf(rl[2 * j], rl[2 * j + 1]);
      }
      xh[nt2] = H.v; xl[nt2] = L.v;
    }
#pragma unroll
    for (int t = 0; t < 5; t++) {
      const int ot = w + t * 4;
      const size_t woff = (size_t)(ot * 16 + lo) * CCH + ck + hi * 8;
      bf16x8 wh = *(const bf16x8*)(whi + woff);
      bf16x8 wl = *(const bf16x8*)(wlo + woff);
#pragma unroll
      for (int nt2 = 0; nt2 < 2; nt2++) {
        if (t == 0) {   // Q/K: D[row=o][col=n]
          acc[t][nt2] = mfma16(wh, xh[nt2], acc[t][nt2]);
          acc[t][nt2] = mfma16(wh, xl[nt2], acc[t][nt2]);
          acc[t][nt2] = mfma16(wl, xh[nt2], acc[t][nt2]);
        } else {        // V: D[row=n][col=c]
          acc[t][nt2] = mfma16(xh[nt2], wh, acc[t][nt2]);
          acc[t][nt2] = mfma16(xl[nt2], wh, acc[t][nt2]);
          acc[t][nt2] = mfma16(xh[nt2], wl, acc[t][nt2]);
        }
      }
    }
  }

  {
    const float* bsrc = (w < 2) ? bq : bk;
    const float  sc   = (w < 2) ? LOG2E : 1.0f;
    float4 b4 = *(const float4*)(bsrc + (w & 1) * 16 + hi * 4);
    float b0 = b4.x * sc, b1 = b4.y * sc, b2 = b4.z * sc, b3 = b4.w * sc;
    u16* base = (w < 2) ? Qo : Ko;
#pragma unroll
    for (int nt2 = 0; nt2 < 2; nt2++) {
      int n = n0 + nt2 * 16 + lo;
      f32x4 a = acc[0][nt2];
      uint2 pk = { pkbf(a[0] + b0, a[1] + b1), pkbf(a[2] + b2, a[3] + b3) };
      *(uint2*)(base + ((size_t)b * NTOK + n) * CQK + (w & 1) * 16 + hi * 4) = pk;
    }
  }
  // V epilogue -> tiled layout.
  {
    const int chk = n0 >> 6;
    const int mh  = (n0 >> 5) & 1;
    u16* vtb = Vo + ((size_t)b * 64 + chk) * 16384 + mh * 512 + (hi * 16 + lo) * 8;
#pragma unroll
    for (int t = 1; t < 5; t++) {
      int ct = w + t * 4 - 4;
      float bvc = bv[ct * 16 + lo];
#pragma unroll
      for (int nt2 = 0; nt2 < 2; nt2++) {
        f32x4 a = acc[t][nt2];
        uint2 pk = { pkbf(a[0] + bvc, a[1] + bvc), pkbf(a[2] + bvc, a[3] + bvc) };
        *(uint2*)(vtb + (size_t)ct * 1024 + nt2 * 4) = pk;
      }
    }
  }
}

// ---------------- Kernel 2: flash attention, 32-q blocks, 4 waves/SIMD -------
// R13 per-wave structure unchanged (best verified), but block = 32 queries /
// 256 thr / 4 waves = (ch2, mh), grid 512 -> 2 blocks/CU = 4 waves/SIMD
// (VGPR 104 fits the 128-reg budget). Doubles TLP to hide the ~1100cy/chunk
// exposed latency; per-CU traffic and VALU work unchanged. Main loop stays
// barrier-free; mh-partner O/l combine at the end (single barrier).
__attribute__((amdgpu_waves_per_eu(4, 4)))
__global__ __launch_bounds__(256) void attn(
    const float* __restrict__ x,
    const u16* __restrict__ Qm, const u16* __restrict__ Km,
    const u16* __restrict__ Vm, float* __restrict__ out)
{
  const int g   = blockIdx.x;
  const int lw3 = g & 7;
  const int b   = lw3 >> 1;                      // batch -> XCD pair
  const int qt5 = ((g >> 3) << 1) | (lw3 & 1);   // 0..127: 32-q tile index
  const int q0  = qt5 * 32;

  const int tid  = threadIdx.x;
  const int w    = tid >> 6;             // 0..3
  const int lane = tid & 63;
  const int lo   = lane & 15;
  const int hi   = lane >> 4;
  const int ch2  = w >> 1;               // 0/1: c 128-half
  const int mh   = w & 1;                // 0/1: m 32-half
  const int qA   = q0;
  const int qB   = q0 + 16;
  const int ct0  = ch2 * 8;              // first of 8 c-tiles

  __shared__ f32x4 Ox[2][2][8][64];      // 32KB: partial O exchange (per ch2)
  __shared__ f32x4 Lx[2][2][64];         // 4KB:  partial l exchange

  const f32x4 fz = { 0.f, 0.f, 0.f, 0.f };
  const u16* Kb = Km + (size_t)b * NTOK * CQK;
  const u16* Vt = Vm + (size_t)b * 64 * 16384 + (size_t)ct0 * 1024
                 + mh * 512 + lane * 8;

  const bf16x8 qfA = *(const bf16x8*)(Qm + ((size_t)b * NTOK + qA + lo) * CQK + hi * 8);
  const bf16x8 qfB = *(const bf16x8*)(Qm + ((size_t)b * NTOK + qB + lo) * CQK + hi * 8);

  bfu onesu;
#pragma unroll
  for (int j = 0; j < 8; j++) onesu.s[j] = 0x3F80;
  const bf16x8 ones = onesu.v;

  f32x4 acc[2][8];
#pragma unroll
  for (int t = 0; t < 2; t++)
#pragma unroll
    for (int ct = 0; ct < 8; ct++) acc[t][ct] = fz;
  f32x4 acc_lA = fz, acc_lB = fz;   // partial l (this m-half), rows 4hi+r

  bf16x8 vfA[8], vfB[8];            // V frags for the 8 c-tiles (1KB each)
  bf16x8 kfA[2], kfB[2];
  u32x4 pEA, pEB, pOA, pOB;         // P fragments (q-tile A/B, even/odd chunk)

#define LD_VF(buf, chk) do {                                                   \
    const u16* vc_ = Vt + (size_t)(chk) * 16384;                               \
    _Pragma("unroll")                                                          \
    for (int ct_ = 0; ct_ < 8; ct_++)                                          \
      buf[ct_] = *(const bf16x8*)(vc_ + ct_ * 1024);                           \
  } while (0)

#define LD_KF(buf, chk) do {                                                   \
    const size_t m0_ = (size_t)(chk) * 64 + mh * 32;                           \
    buf[0] = *(const bf16x8*)(Kb + (m0_ +  0 + lo) * CQK + hi * 8);            \
    buf[1] = *(const bf16x8*)(Kb + (m0_ + 16 + lo) * CQK + hi * 8);            \
  } while (0)

  // QK^T + exp2 + pack for one q-tile over this wave's 32-m half.
  // Result element j corresponds to m_rel = 16*(j>>2) + 4hi + (j&3) — the
  // tiled-V slot order, so it is directly the PV A-fragment.
  auto produce = [&](const bf16x8* kf, bf16x8 qf) -> u32x4 {
    f32x4 s0 = mfma16(kf[0], qf, fz);
    f32x4 s1 = mfma16(kf[1], qf, fz);
#pragma unroll
    for (int r = 0; r < 4; r++) {
      s0[r] = __builtin_amdgcn_exp2f(s0[r]);
      s1[r] = __builtin_amdgcn_exp2f(s1[r]);
    }
    u32x4 o;
    o[0] = pkbf(s0[0], s0[1]); o[1] = pkbf(s0[2], s0[3]);
    o[2] = pkbf(s1[0], s1[1]); o[3] = pkbf(s1[2], s1[3]);
    return o;
  };

#define PV(pA, pB, vbuf) do {                                                  \
    const bf16x8 aA = __builtin_bit_cast(bf16x8, pA);                          \
    const bf16x8 aB = __builtin_bit_cast(bf16x8, pB);                          \
    _Pragma("unroll")                                                          \
    for (int ct_ = 0; ct_ < 8; ct_++) {                                        \
      acc[0][ct_] = mfma16(aA, vbuf[ct_], acc[0][ct_]);                        \
      acc[1][ct_] = mfma16(aB, vbuf[ct_], acc[1][ct_]);                        \
    }                                                                          \
    acc_lA = mfma16(aA, ones, acc_lA);                                         \
    acc_lB = mfma16(aB, ones, acc_lB);                                         \
  } while (0)

  // Prologue: V(0) in flight early; P(0) from K(0); K(1) into kfA.
  LD_KF(kfA, 0);
  LD_VF(vfA, 0);
  pEA = produce(kfA, qfA);
  pEB = produce(kfA, qfB);
  LD_KF(kfA, 1);

  for (int ch = 0; ch < 64; ch += 2) {
    // even body: consume vfA / pE*; kfA holds K(ch+1).
    if (ch + 1 < 64) LD_VF(vfB, ch + 1);
    if (ch + 2 < 64) LD_KF(kfB, ch + 2);
    if (ch + 1 < 64) { pOA = produce(kfA, qfA); pOB = produce(kfA, qfB); }
    PV(pEA, pEB, vfA);

    // odd body: consume vfB / pO*; kfB holds K(ch+2).
    if (ch + 1 < 64) {
      if (ch + 2 < 64) LD_VF(vfA, ch + 2);
      if (ch + 3 < 64) LD_KF(kfA, ch + 3);
      if (ch + 2 < 64) { pEA = produce(kfB, qfA); pEB = produce(kfB, qfB); }
      PV(pOA, pOB, vfB);
    }
  }
#undef LD_VF
#undef LD_KF
#undef PV

  // Epilogue: combine m-half partners (w, w^1) via LDS; single barrier.
  if (mh == 1) {
#pragma unroll
    for (int t = 0; t < 2; t++)
#pragma unroll
      for (int ct = 0; ct < 8; ct++) Ox[ch2][t][ct][lane] = acc[t][ct];
    Lx[ch2][0][lane] = acc_lA;
    Lx[ch2][1][lane] = acc_lB;
  }
  __syncthreads();
  if (mh == 0) {
    const float* xb = x   + (size_t)b * CCH * NTOK;
    float*       ob = out + (size_t)b * CCH * NTOK;
#pragma unroll
    for (int t = 0; t < 2; t++) {
      const int qbase = (t == 0) ? qA : qB;
      f32x4 lp = ((t == 0) ? acc_lA : acc_lB) + Lx[ch2][t][lane];
      f32x4 il;
#pragma unroll
      for (int r = 0; r < 4; r++) il[r] = 1.f / lp[r];
#pragma unroll
      for (int ct = 0; ct < 8; ct++) {
        f32x4 tot = acc[t][ct] + Ox[ch2][t][ct][lane];
        int c = (ct0 + ct) * 16 + lo;
        size_t base = (size_t)c * NTOK + qbase + hi * 4;
        float4 xr = *(const float4*)(xb + base);
        float4 o;
        o.x = tot[0] * il[0] + xr.x;
        o.y = tot[1] * il[1] + xr.y;
        o.z = tot[2] * il[2] + xr.z;
        o.w = tot[3] * il[3] + xr.w;
        *(float4*)(ob + base) = o;
      }
    }
  }
}

extern "C" void kernel_launch(void* const* d_in, const int* in_sizes, int n_in,
                              void* d_out, int out_size, void* d_ws, size_t ws_size,
                              hipStream_t stream) {
  const float* x  = (const float*)d_in[0];
  const float* wq = (const float*)d_in[1];
  const float* bq = (const float*)d_in[2];
  const float* wk = (const float*)d_in[3];
  const float* bk = (const float*)d_in[4];
  const float* wv = (const float*)d_in[5];
  const float* bv = (const float*)d_in[6];
  float* out = (float*)d_out;

  // ws (bf16): Q [4,4096,32] | K [4,4096,32] | V tiled [4][64][16][2][512]
  // | Whi,Wlo [320,256]
  u16* Qp  = (u16*)d_ws;
  u16* Kp  = Qp + (size_t)NB * NTOK * CQK;
  u16* Vp  = Kp + (size_t)NB * NTOK * CQK;
  u16* Whi = Vp + (size_t)NB * CCH * NTOK;
  u16* Wlo = Whi + (size_t)320 * CCH;

  convert_w<<<80, 256, 0, stream>>>(wq, wk, wv, Whi, Wlo);
  dim3 pg(128, NB);
  qkv_proj<<<pg, 256, 0, stream>>>(x, bq, bk, bv, Whi, Wlo, Qp, Kp, Vp);
  attn<<<512, 256, 0, stream>>>(x, Qp, Kp, Vp, out);
}

// Round 18
// 91.343 us; speedup vs baseline: 4.7161x; 4.7161x over previous
//
#include <hip/hip_runtime.h>
#include <hip/hip_bf16.h>

#define NB   4
#define CCH  256
#define CQK  32
#define NTOK 4096
#define LOG2E 1.4426950408889634f

typedef unsigned short u16;
typedef unsigned int   u32;
typedef __attribute__((ext_vector_type(8))) __bf16 bf16x8;
typedef __attribute__((ext_vector_type(4))) float  f32x4;
typedef __attribute__((ext_vector_type(4))) u32    u32x4;

union bfu { bf16x8 v; u16 s[8]; u32 w[4]; };

static __device__ __forceinline__ u16 f2bf(float f) {
  union { __hip_bfloat16 h; u16 u; } c; c.h = __float2bfloat16(f); return c.u;
}
static __device__ __forceinline__ float bf2f(u16 u) {
  union { __hip_bfloat16 h; u16 u; } c; c.u = u; return __bfloat162float(c.h);
}
// Safe packed f32->bf16 pair (round-half-up, ~ulp of RNE). Plain integer ops
// (R11's v_cvt_pk_bf16_f32 asm was the correctness poison — do not reuse).
static __device__ __forceinline__ u32 pkbf(float a, float b) {
  u32 ua = __builtin_bit_cast(u32, a) + 0x8000u;
  u32 ub = __builtin_bit_cast(u32, b) + 0x8000u;
  return (ua >> 16) | (ub & 0xFFFF0000u);
}
static __device__ __forceinline__ f32x4 mfma16(bf16x8 a, bf16x8 b, f32x4 c) {
  return __builtin_amdgcn_mfma_f32_16x16x32_bf16(a, b, c, 0, 0, 0);
}

// V tiled layout (since R9): per (b, ch=m/64) a contiguous 32KB slab
// [ct 16][mh 2][512 u16]; u16 slot (hi*16+lo)*8+j =
// V[m=ch*64+mh*32+16*(j>>2)+4hi+(j&3)][c=ct*16+lo].

// ---------------- Kernel 0: split W to bf16 hi/lo (once, tiny) ----------------
__global__ __launch_bounds__(256) void convert_w(
    const float* __restrict__ wq, const float* __restrict__ wk,
    const float* __restrict__ wv, u16* __restrict__ whi, u16* __restrict__ wlo)
{
  int i   = blockIdx.x * 256 + threadIdx.x;  // float4 index, 320*64 total
  int row = i >> 6;
  int col = (i & 63) * 4;
  const float* src = (row < 32) ? wq + row * CCH
                   : (row < 64) ? wk + (row - 32) * CCH
                                : wv + (row - 64) * CCH;
  float sc = (row < 32) ? LOG2E : 1.0f;
  float4 v = *(const float4*)(src + col);
  float f[4] = { v.x * sc, v.y * sc, v.z * sc, v.w * sc };
  u16 h[4], l[4];
#pragma unroll
  for (int j = 0; j < 4; j++) {
    h[j] = f2bf(f[j]);
    l[j] = f2bf(f[j] - bf2f(h[j]));
  }
  uint2 ph = { (u32)h[0] | ((u32)h[1] << 16), (u32)h[2] | ((u32)h[3] << 16) };
  uint2 pl = { (u32)l[0] | ((u32)l[1] << 16), (u32)l[2] | ((u32)l[3] << 16) };
  *(uint2*)(whi + (size_t)i * 4) = ph;
  *(uint2*)(wlo + (size_t)i * 4) = pl;
}

// ---------------- Kernel 1: MFMA QKV projection (R13 version: n-tile 32) -----
__attribute__((amdgpu_waves_per_eu(2, 4)))
__global__ __launch_bounds__(256) void qkv_proj(
    const float* __restrict__ x,
    const float* __restrict__ bq, const float* __restrict__ bk,
    const float* __restrict__ bv,
    const u16* __restrict__ whi, const u16* __restrict__ wlo,
    u16* __restrict__ Qo, u16* __restrict__ Ko, u16* __restrict__ Vo)
{
  const int nt = blockIdx.x;
  const int b  = blockIdx.y;
  const int n0 = nt * 32;
  const int tid = threadIdx.x;
  const int w = tid >> 6, lane = tid & 63, lo = lane & 15, hi = lane >> 4;

  const f32x4 fz = { 0.f, 0.f, 0.f, 0.f };
  f32x4 acc[5][2];
#pragma unroll
  for (int t = 0; t < 5; t++) { acc[t][0] = fz; acc[t][1] = fz; }

  const float* xb = x + (size_t)b * CCH * NTOK;

  for (int k = 0; k < 8; k++) {
    const int ck = k * 32;
    bf16x8 xh[2], xl[2];
#pragma unroll
    for (int nt2 = 0; nt2 < 2; nt2++) {
      const float* xc = xb + (size_t)(ck + hi * 8) * NTOK + n0 + nt2 * 16 + lo;
      u32  bw[8];
      float rl[8];
#pragma unroll
      for (int j = 0; j < 8; j++) {
        float f  = xc[(size_t)j * NTOK];
        u32 bits = __builtin_bit_cast(u32, f);
        float fh = __builtin_bit_cast(float, bits & 0xFFFF0000u);
        bw[j] = bits;
        rl[j] = f - fh;
      }
      bfu H, L;
#pragma unroll
      for (int j = 0; j < 4; j++) {
        H.w[j] = (bw[2 * j] >> 16) | (bw[2 * j + 1] & 0xFFFF0000u);
        L.w[j] = pkbf(rl[2 * j], rl[2 * j + 1]);
      }
      xh[nt2] = H.v; xl[nt2] = L.v;
    }
#pragma unroll
    for (int t = 0; t < 5; t++) {
      const int ot = w + t * 4;
      const size_t woff = (size_t)(ot * 16 + lo) * CCH + ck + hi * 8;
      bf16x8 wh = *(const bf16x8*)(whi + woff);
      bf16x8 wl = *(const bf16x8*)(wlo + woff);
#pragma unroll
      for (int nt2 = 0; nt2 < 2; nt2++) {
        if (t == 0) {   // Q/K: D[row=o][col=n]
          acc[t][nt2] = mfma16(wh, xh[nt2], acc[t][nt2]);
          acc[t][nt2] = mfma16(wh, xl[nt2], acc[t][nt2]);
          acc[t][nt2] = mfma16(wl, xh[nt2], acc[t][nt2]);
        } else {        // V: D[row=n][col=c]
          acc[t][nt2] = mfma16(xh[nt2], wh, acc[t][nt2]);
          acc[t][nt2] = mfma16(xl[nt2], wh, acc[t][nt2]);
          acc[t][nt2] = mfma16(xh[nt2], wl, acc[t][nt2]);
        }
      }
    }
  }

  {
    const float* bsrc = (w < 2) ? bq : bk;
    const float  sc   = (w < 2) ? LOG2E : 1.0f;
    float4 b4 = *(const float4*)(bsrc + (w & 1) * 16 + hi * 4);
    float b0 = b4.x * sc, b1 = b4.y * sc, b2 = b4.z * sc, b3 = b4.w * sc;
    u16* base = (w < 2) ? Qo : Ko;
#pragma unroll
    for (int nt2 = 0; nt2 < 2; nt2++) {
      int n = n0 + nt2 * 16 + lo;
      f32x4 a = acc[0][nt2];
      uint2 pk = { pkbf(a[0] + b0, a[1] + b1), pkbf(a[2] + b2, a[3] + b3) };
      *(uint2*)(base + ((size_t)b * NTOK + n) * CQK + (w & 1) * 16 + hi * 4) = pk;
    }
  }
  // V epilogue -> tiled layout.
  {
    const int chk = n0 >> 6;
    const int mh  = (n0 >> 5) & 1;
    u16* vtb = Vo + ((size_t)b * 64 + chk) * 16384 + mh * 512 + (hi * 16 + lo) * 8;
#pragma unroll
    for (int t = 1; t < 5; t++) {
      int ct = w + t * 4 - 4;
      float bvc = bv[ct * 16 + lo];
#pragma unroll
      for (int nt2 = 0; nt2 < 2; nt2++) {
        f32x4 a = acc[t][nt2];
        uint2 pk = { pkbf(a[0] + bvc, a[1] + bvc), pkbf(a[2] + bvc, a[3] + bvc) };
        *(uint2*)(vtb + (size_t)ct * 1024 + nt2 * 4) = pk;
      }
    }
  }
}

// ---------------- Kernel 2: flash attention, 32-q blocks ----------------
// R17 structure (32-q / 256-thr / 4-wave blocks, grid 512) but with
// waves_per_eu(2,2) — the ONLY attribute setting that has produced sane
// allocation on this wave code (R13: 104 VGPR, no spill). Budget 256;
// runtime occupancy then = min(VGPR-fit ~4 waves/SIMD, LDS-fit 4 blocks/CU)
// -> up to 2x R13's TLP without the R17 spill disaster (that was
// waves_per_eu(4,4) compressing to 64 regs + 600MB scratch).
__attribute__((amdgpu_waves_per_eu(2, 2)))
__global__ __launch_bounds__(256) void attn(
    const float* __restrict__ x,
    const u16* __restrict__ Qm, const u16* __restrict__ Km,
    const u16* __restrict__ Vm, float* __restrict__ out)
{
  const int g   = blockIdx.x;
  const int lw3 = g & 7;
  const int b   = lw3 >> 1;                      // batch -> XCD pair
  const int qt5 = ((g >> 3) << 1) | (lw3 & 1);   // 0..127: 32-q tile index
  const int q0  = qt5 * 32;

  const int tid  = threadIdx.x;
  const int w    = tid >> 6;             // 0..3
  const int lane = tid & 63;
  const int lo   = lane & 15;
  const int hi   = lane >> 4;
  const int ch2  = w >> 1;               // 0/1: c 128-half
  const int mh   = w & 1;                // 0/1: m 32-half
  const int qA   = q0;
  const int qB   = q0 + 16;
  const int ct0  = ch2 * 8;              // first of 8 c-tiles

  __shared__ f32x4 Ox[2][2][8][64];      // 32KB: partial O exchange (per ch2)
  __shared__ f32x4 Lx[2][2][64];         // 4KB:  partial l exchange

  const f32x4 fz = { 0.f, 0.f, 0.f, 0.f };
  const u16* Kb = Km + (size_t)b * NTOK * CQK;
  const u16* Vt = Vm + (size_t)b * 64 * 16384 + (size_t)ct0 * 1024
                 + mh * 512 + lane * 8;

  const bf16x8 qfA = *(const bf16x8*)(Qm + ((size_t)b * NTOK + qA + lo) * CQK + hi * 8);
  const bf16x8 qfB = *(const bf16x8*)(Qm + ((size_t)b * NTOK + qB + lo) * CQK + hi * 8);

  bfu onesu;
#pragma unroll
  for (int j = 0; j < 8; j++) onesu.s[j] = 0x3F80;
  const bf16x8 ones = onesu.v;

  f32x4 acc[2][8];
#pragma unroll
  for (int t = 0; t < 2; t++)
#pragma unroll
    for (int ct = 0; ct < 8; ct++) acc[t][ct] = fz;
  f32x4 acc_lA = fz, acc_lB = fz;   // partial l (this m-half), rows 4hi+r

  bf16x8 vfA[8], vfB[8];            // V frags for the 8 c-tiles (1KB each)
  bf16x8 kfA[2], kfB[2];
  u32x4 pEA, pEB, pOA, pOB;         // P fragments (q-tile A/B, even/odd chunk)

#define LD_VF(buf, chk) do {                                                   \
    const u16* vc_ = Vt + (size_t)(chk) * 16384;                               \
    _Pragma("unroll")                                                          \
    for (int ct_ = 0; ct_ < 8; ct_++)                                          \
      buf[ct_] = *(const bf16x8*)(vc_ + ct_ * 1024);                           \
  } while (0)

#define LD_KF(buf, chk) do {                                                   \
    const size_t m0_ = (size_t)(chk) * 64 + mh * 32;                           \
    buf[0] = *(const bf16x8*)(Kb + (m0_ +  0 + lo) * CQK + hi * 8);            \
    buf[1] = *(const bf16x8*)(Kb + (m0_ + 16 + lo) * CQK + hi * 8);            \
  } while (0)

  // QK^T + exp2 + pack for one q-tile over this wave's 32-m half.
  // Result element j corresponds to m_rel = 16*(j>>2) + 4hi + (j&3) — the
  // tiled-V slot order, so it is directly the PV A-fragment.
  auto produce = [&](const bf16x8* kf, bf16x8 qf) -> u32x4 {
    f32x4 s0 = mfma16(kf[0], qf, fz);
    f32x4 s1 = mfma16(kf[1], qf, fz);
#pragma unroll
    for (int r = 0; r < 4; r++) {
      s0[r] = __builtin_amdgcn_exp2f(s0[r]);
      s1[r] = __builtin_amdgcn_exp2f(s1[r]);
    }
    u32x4 o;
    o[0] = pkbf(s0[0], s0[1]); o[1] = pkbf(s0[2], s0[3]);
    o[2] = pkbf(s1[0], s1[1]); o[3] = pkbf(s1[2], s1[3]);
    return o;
  };

#define PV(pA, pB, vbuf) do {                                                  \
    const bf16x8 aA = __builtin_bit_cast(bf16x8, pA);                          \
    const bf16x8 aB = __builtin_bit_cast(bf16x8, pB);                          \
    _Pragma("unroll")                                                          \
    for (int ct_ = 0; ct_ < 8; ct_++) {                                        \
      acc[0][ct_] = mfma16(aA, vbuf[ct_], acc[0][ct_]);                        \
      acc[1][ct_] = mfma16(aB, vbuf[ct_], acc[1][ct_]);                        \
    }                                                                          \
    acc_lA = mfma16(aA, ones, acc_lA);                                         \
    acc_lB = mfma16(aB, ones, acc_lB);                                         \
  } while (0)

  // Prologue: V(0) in flight early; P(0) from K(0); K(1) into kfA.
  LD_KF(kfA, 0);
  LD_VF(vfA, 0);
  pEA = produce(kfA, qfA);
  pEB = produce(kfA, qfB);
  LD_KF(kfA, 1);

  for (int ch = 0; ch < 64; ch += 2) {
    // even body: consume vfA / pE*; kfA holds K(ch+1).
    if (ch + 1 < 64) LD_VF(vfB, ch + 1);
    if (ch + 2 < 64) LD_KF(kfB, ch + 2);
    if (ch + 1 < 64) { pOA = produce(kfA, qfA); pOB = produce(kfA, qfB); }
    PV(pEA, pEB, vfA);

    // odd body: consume vfB / pO*; kfB holds K(ch+2).
    if (ch + 1 < 64) {
      if (ch + 2 < 64) LD_VF(vfA, ch + 2);
      if (ch + 3 < 64) LD_KF(kfA, ch + 3);
      if (ch + 2 < 64) { pEA = produce(kfB, qfA); pEB = produce(kfB, qfB); }
      PV(pOA, pOB, vfB);
    }
  }
#undef LD_VF
#undef LD_KF
#undef PV

  // Epilogue: combine m-half partners (w, w^1) via LDS; single barrier.
  if (mh == 1) {
#pragma unroll
    for (int t = 0; t < 2; t++)
#pragma unroll
      for (int ct = 0; ct < 8; ct++) Ox[ch2][t][ct][lane] = acc[t][ct];
    Lx[ch2][0][lane] = acc_lA;
    Lx[ch2][1][lane] = acc_lB;
  }
  __syncthreads();
  if (mh == 0) {
    const float* xb = x   + (size_t)b * CCH * NTOK;
    float*       ob = out + (size_t)b * CCH * NTOK;
#pragma unroll
    for (int t = 0; t < 2; t++) {
      const int qbase = (t == 0) ? qA : qB;
      f32x4 lp = ((t == 0) ? acc_lA : acc_lB) + Lx[ch2][t][lane];
      f32x4 il;
#pragma unroll
      for (int r = 0; r < 4; r++) il[r] = 1.f / lp[r];
#pragma unroll
      for (int ct = 0; ct < 8; ct++) {
        f32x4 tot = acc[t][ct] + Ox[ch2][t][ct][lane];
        int c = (ct0 + ct) * 16 + lo;
        size_t base = (size_t)c * NTOK + qbase + hi * 4;
        float4 xr = *(const float4*)(xb + base);
        float4 o;
        o.x = tot[0] * il[0] + xr.x;
        o.y = tot[1] * il[1] + xr.y;
        o.z = tot[2] * il[2] + xr.z;
        o.w = tot[3] * il[3] + xr.w;
        *(float4*)(ob + base) = o;
      }
    }
  }
}

extern "C" void kernel_launch(void* const* d_in, const int* in_sizes, int n_in,
                              void* d_out, int out_size, void* d_ws, size_t ws_size,
                              hipStream_t stream) {
  const float* x  = (const float*)d_in[0];
  const float* wq = (const float*)d_in[1];
  const float* bq = (const float*)d_in[2];
  const float* wk = (const float*)d_in[3];
  const float* bk = (const float*)d_in[4];
  const float* wv = (const float*)d_in[5];
  const float* bv = (const float*)d_in[6];
  float* out = (float*)d_out;

  // ws (bf16): Q [4,4096,32] | K [4,4096,32] | V tiled [4][64][16][2][512]
  // | Whi,Wlo [320,256]
  u16* Qp  = (u16*)d_ws;
  u16* Kp  = Qp + (size_t)NB * NTOK * CQK;
  u16* Vp  = Kp + (size_t)NB * NTOK * CQK;
  u16* Whi = Vp + (size_t)NB * CCH * NTOK;
  u16* Wlo = Whi + (size_t)320 * CCH;

  convert_w<<<80, 256, 0, stream>>>(wq, wk, wv, Whi, Wlo);
  dim3 pg(128, NB);
  qkv_proj<<<pg, 256, 0, stream>>>(x, bq, bk, bv, Whi, Wlo, Qp, Kp, Vp);
  attn<<<512, 256, 0, stream>>>(x, Qp, Kp, Vp, out);
}